// Round 1
// 424.862 us; speedup vs baseline: 1.0217x; 1.0217x over previous
//
#include <hip/hip_runtime.h>
#include <hip/hip_bf16.h>
#include <stdint.h>

#define Bn 8
#define Tn 4096
#define En 1024
#define Hn 128
#define SCALE 0.08838834764831845f  // 1/sqrt(128)

typedef __attribute__((ext_vector_type(8))) short bf16x8;
typedef __attribute__((ext_vector_type(4))) float f32x4;

__device__ __forceinline__ float bf2f(unsigned short v) {
    return __uint_as_float(((unsigned int)v) << 16);
}
// RNE pack of two fp32 -> packed bf16x2 (v_cvt_pk_bf16_f32 on gfx950)
__device__ __forceinline__ unsigned int pkbf(float a, float b) {
    __hip_bfloat162 h = __float22bfloat162_rn(make_float2(a, b));
    union { __hip_bfloat162 h2; unsigned int u; } cv;
    cv.h2 = h;
    return cv.u;
}

// ---------------------------------------------------------------------------
// QKV projection via MFMA, software-pipelined staging. (unchanged this round)
// grid (256, 3): x = 128-row M tile, y = which {Q,K,V}. Same-mt triplet ->
// same linear-id mod-256 slot -> same CU/XCD: x tile read once from HBM.
// block 256 = 4 waves; wave owns 32 rows. BK=64. LDS 36 KB.
// ---------------------------------------------------------------------------
__global__ __launch_bounds__(256)
void qkv_mfma(const float* __restrict__ x,
              const float* __restrict__ Wq,
              const float* __restrict__ Wk,
              const float* __restrict__ Wv,
              unsigned short* __restrict__ Qo,
              unsigned short* __restrict__ Ko,
              unsigned short* __restrict__ Vo) {
    const int mt = blockIdx.x;
    const int which = blockIdx.y;
    const float* W = (which == 0) ? Wq : (which == 1) ? Wk : Wv;
    unsigned short* out = (which == 0) ? Qo : (which == 1) ? Ko : Vo;
    const float scale = (which == 0) ? SCALE : 1.0f;

    __shared__ alignas(16) unsigned short Xs[128 * 72];  // [m][k] bf16, pad 72
    __shared__ alignas(16) unsigned short Wt[128 * 72];  // [n][k] bf16 (transposed)

    const int t = threadIdx.x;
    const int w = t >> 6;
    const int lane = t & 63;
    const int quad = lane >> 4;
    const int l16 = lane & 15;

    // staging coords
    const int xrow = t >> 1;              // 0..127
    const int xkc = (t & 1) * 32;         // 0 or 32
    const int ws0 = (t & 31) * 2;         // k pair 0..62
    const int wd0 = (t >> 5) * 16;        // n group 0..112

    const float* xsrc0 = x + (size_t)(mt * 128 + xrow) * En + xkc;

    f32x4 acc[2][8];
#pragma unroll
    for (int mi = 0; mi < 2; ++mi)
#pragma unroll
        for (int nst = 0; nst < 8; ++nst) acc[mi][nst] = (f32x4){0.f, 0.f, 0.f, 0.f};

    // ---- prefetch tile 0 ----
    float4 xpre[8], wpre[8];
    {
        const float* src = xsrc0;
#pragma unroll
        for (int i = 0; i < 8; ++i) xpre[i] = *(const float4*)(src + i * 4);
        const float* w0 = W + (size_t)ws0 * Hn + wd0;
        const float* w1 = w0 + Hn;
#pragma unroll
        for (int i = 0; i < 4; ++i) wpre[i] = *(const float4*)(w0 + i * 4);
#pragma unroll
        for (int i = 0; i < 4; ++i) wpre[4 + i] = *(const float4*)(w1 + i * 4);
    }

    for (int kt = 0; kt < 16; ++kt) {
        __syncthreads();
        // ---- write staged regs -> LDS (cvt fp32->bf16) ----
        {
            unsigned int u[16];
#pragma unroll
            for (int i = 0; i < 8; ++i) {
                u[2 * i]     = pkbf(xpre[i].x, xpre[i].y);
                u[2 * i + 1] = pkbf(xpre[i].z, xpre[i].w);
            }
#pragma unroll
            for (int i = 0; i < 4; ++i)
                *(uint4*)&Xs[xrow * 72 + xkc + i * 8] = ((const uint4*)u)[i];

            const float* ax = (const float*)&wpre[0];
            const float* bx = (const float*)&wpre[4];
#pragma unroll
            for (int dd = 0; dd < 16; ++dd)
                *(unsigned int*)&Wt[(wd0 + dd) * 72 + ws0] = pkbf(ax[dd], bx[dd]);
        }
        // ---- issue next tile's global loads ----
        if (kt < 15) {
            const float* src = xsrc0 + (kt + 1) * 64;
#pragma unroll
            for (int i = 0; i < 8; ++i) xpre[i] = *(const float4*)(src + i * 4);
            const float* w0 = W + (size_t)((kt + 1) * 64 + ws0) * Hn + wd0;
            const float* w1 = w0 + Hn;
#pragma unroll
            for (int i = 0; i < 4; ++i) wpre[i] = *(const float4*)(w0 + i * 4);
#pragma unroll
            for (int i = 0; i < 4; ++i) wpre[4 + i] = *(const float4*)(w1 + i * 4);
        }
        __syncthreads();

        // ---- MFMA: 32 per wave per k-tile ----
#pragma unroll
        for (int ks = 0; ks < 2; ++ks) {
            bf16x8 af[2];
#pragma unroll
            for (int mi = 0; mi < 2; ++mi)
                af[mi] = *(const bf16x8*)&Xs[(w * 32 + mi * 16 + l16) * 72 + ks * 32 + quad * 8];
#pragma unroll
            for (int nst = 0; nst < 8; ++nst) {
                bf16x8 bfr = *(const bf16x8*)&Wt[(nst * 16 + l16) * 72 + ks * 32 + quad * 8];
                acc[0][nst] = __builtin_amdgcn_mfma_f32_16x16x32_bf16(bfr, af[0], acc[0][nst], 0, 0, 0);
                acc[1][nst] = __builtin_amdgcn_mfma_f32_16x16x32_bf16(bfr, af[1], acc[1][nst], 0, 0, 0);
            }
        }
    }

    // ---- epilogue: lane holds m = l16, n = nst*16 + quad*4 + r ----
#pragma unroll
    for (int mi = 0; mi < 2; ++mi) {
        const size_t rowbase = (size_t)(mt * 128 + w * 32 + mi * 16 + l16) * Hn;
#pragma unroll
        for (int nst = 0; nst < 8; ++nst) {
            f32x4 v = acc[mi][nst];
            uint2 pk;
            pk.x = pkbf(v[0] * scale, v[1] * scale);
            pk.y = pkbf(v[2] * scale, v[3] * scale);
            *(uint2*)(out + rowbase + nst * 16 + quad * 4) = pk;
        }
    }
}

// ---------------------------------------------------------------------------
// MFMA flash attention v2: in-block KV-split (even/odd) across wave groups.
// grid (8, 64): x = batch (XCD = batch: K/V 2.1 MB fits per-XCD L2), y -> qt.
// block 512 = 8 waves. Group g = waves 4g..4g+3 processes kv tiles kt%2 == g;
// each group keeps its own online-softmax state; in-block flash-combine at
// the end. Halves the serial kv-chain of the heaviest tile (64 -> 32 rounds).
// LDS 80 KB dynamic (2xK[64][128] + 2xV^T[128][64] + 8xP[16][64], all
// XOR-swizzled: byte ^= (row&7)<<4 -> bank-conflict-free, no pads needed).
// 2 blocks/CU resident (160 KB), 16 waves/CU.
// ---------------------------------------------------------------------------
#define KSWZ(r, c) (((r) << 8) + ((c) ^ (((r) & 7) << 4)))  // 256B rows (K/Q)
#define VSWZ(r, c) (((r) << 7) + ((c) ^ (((r) & 7) << 4)))  // 128B rows (V/P)

__global__ __launch_bounds__(512, 4)
void flash_mfma(const unsigned short* __restrict__ Qb,
                const unsigned short* __restrict__ Kb,
                const unsigned short* __restrict__ Vb,
                float* __restrict__ out) {
    const int b = blockIdx.x;                     // batch
    const int bx = blockIdx.y;
    const int qt = (bx < 32) ? (63 - bx) : (bx - 32);
    const int t = threadIdx.x;
    const int w = t >> 6;                         // 0..7
    const int g = w >> 2;                         // kv-parity group (0=even,1=odd)
    const int rg = w & 3;                         // q row-group within group
    const int lane = t & 63;
    const int quad = lane >> 4;
    const int l16 = lane & 15;
    const int t256 = t & 255;                     // group-local thread id

    extern __shared__ unsigned short pool[];      // 40960 shorts = 80 KB
    char* const poolb = (char*)pool;
    char* const Kg = poolb + g * 16384;           // [64][128] bf16, swizzled
    char* const Vg = poolb + 32768 + g * 16384;   // [128][64] bf16 (V^T), swizzled
    char* const Pw = poolb + 65536 + w * 2048;    // per-wave [16][64] bf16, swizzled
    float* const Os = (float*)poolb;              // [64][132] f32 (epilogue overlay)
    float* const Ex = (float*)(poolb + 40960);    // [4][16][128] f32 (combine overlay)
    float* const Em = (float*)(poolb + 73728);    // [4][16] partial m
    float* const El = Em + 64;                    // [4][16] partial l

    const size_t gbase = (size_t)b * ((size_t)Tn * Hn);
    const unsigned short* kbase = Kb + gbase;
    const unsigned short* vbase = Vb + gbase;

    // staging coords (group-local; K: row-major b128; V: transpose-pack u32)
    const int krow0 = t256 >> 4;                  // 0..15 (+16*i)
    const int kcolB = (t256 & 15) * 16;           // byte col in 256B row
    const int kcolS = (t256 & 15) * 8;            // short col in source
    const int vs0 = (t256 & 31) * 2;
    const int vd0 = (t256 >> 5) * 16;

    // ---- prefetch this group's tile 0 (kt = g) ----
    uint4 kpre[4], vra, vrb, vrc, vrd;
    if (g <= qt) {
        const unsigned short* ksrc = kbase + (size_t)(g * 64) * Hn;
#pragma unroll
        for (int i = 0; i < 4; ++i)
            kpre[i] = *(const uint4*)&ksrc[(krow0 + 16 * i) * 128 + kcolS];
        const unsigned short* vsrc = vbase + (size_t)(g * 64) * Hn;
        vra = *(const uint4*)&vsrc[vs0 * 128 + vd0];
        vrb = *(const uint4*)&vsrc[vs0 * 128 + vd0 + 8];
        vrc = *(const uint4*)&vsrc[(vs0 + 1) * 128 + vd0];
        vrd = *(const uint4*)&vsrc[(vs0 + 1) * 128 + vd0 + 8];
    }

    // ---- stage Q tile (into Ke region), all 512 threads ----
    {
        const unsigned short* qsrc = Qb + gbase + (size_t)(qt * 64) * Hn;
#pragma unroll
        for (int i = 0; i < 2; ++i) {
            const int row = (t >> 4) + 32 * i;    // 0..63
            *(uint4*)(poolb + KSWZ(row, (t & 15) * 16)) =
                *(const uint4*)&qsrc[row * 128 + (t & 15) * 8];
        }
    }
    __syncthreads();

    // hoist Q B-frags: lane holds Q[q=l16 of row-group rg][d=ks*32+quad*8+j]
    bf16x8 qf[4];
#pragma unroll
    for (int ks = 0; ks < 4; ++ks)
        qf[ks] = *(const bf16x8*)(poolb + KSWZ(rg * 16 + l16, ks * 64 + quad * 16));

    f32x4 acc_o[8];
#pragma unroll
    for (int i = 0; i < 8; ++i) acc_o[i] = (f32x4){0.f, 0.f, 0.f, 0.f};
    float m_run = -1e30f, l_run = 0.f;

    const int n = (qt >> 1) + 1;                  // group-A trip count (>= group-B)
    for (int it = 0; it < n; ++it) {
        const int kt = 2 * it + g;
        const bool active = (kt <= qt);
        __syncthreads();
        // ---- write staged regs -> this group's LDS buffers ----
        if (active) {
#pragma unroll
            for (int i = 0; i < 4; ++i)
                *(uint4*)(Kg + KSWZ(krow0 + 16 * i, kcolB)) = kpre[i];
            const unsigned short* pa = (const unsigned short*)&vra;
            const unsigned short* pb = (const unsigned short*)&vrb;
            const unsigned short* pc = (const unsigned short*)&vrc;
            const unsigned short* pd = (const unsigned short*)&vrd;
#pragma unroll
            for (int dd = 0; dd < 8; ++dd)
                *(unsigned int*)(Vg + VSWZ(vd0 + dd, vs0 * 2)) =
                    (unsigned int)pa[dd] | ((unsigned int)pc[dd] << 16);
#pragma unroll
            for (int dd = 0; dd < 8; ++dd)
                *(unsigned int*)(Vg + VSWZ(vd0 + 8 + dd, vs0 * 2)) =
                    (unsigned int)pb[dd] | ((unsigned int)pd[dd] << 16);
        }
        // ---- issue next tile's (kt+2) global loads ----
        if (kt + 2 <= qt) {
            const unsigned short* ksrc = kbase + (size_t)((kt + 2) * 64) * Hn;
#pragma unroll
            for (int i = 0; i < 4; ++i)
                kpre[i] = *(const uint4*)&ksrc[(krow0 + 16 * i) * 128 + kcolS];
            const unsigned short* vsrc = vbase + (size_t)((kt + 2) * 64) * Hn;
            vra = *(const uint4*)&vsrc[vs0 * 128 + vd0];
            vrb = *(const uint4*)&vsrc[vs0 * 128 + vd0 + 8];
            vrc = *(const uint4*)&vsrc[(vs0 + 1) * 128 + vd0];
            vrd = *(const uint4*)&vsrc[(vs0 + 1) * 128 + vd0 + 8];
        }
        __syncthreads();
        if (!active) continue;                    // barriers done; skip compute

        const bool diag = (kt == qt);
        // S^T = K.Q^T ; lane holds S[q=l16][s=st*16+quad*4+r]
        f32x4 sa[4];
#pragma unroll
        for (int st = 0; st < 4; ++st) {
            if (diag && st > rg) {
                sa[st] = (f32x4){-1e30f, -1e30f, -1e30f, -1e30f};  // fully masked
            } else {
                f32x4 c = (f32x4){0.f, 0.f, 0.f, 0.f};
#pragma unroll
                for (int ks = 0; ks < 4; ++ks) {
                    bf16x8 kf = *(const bf16x8*)(Kg + KSWZ(st * 16 + l16, ks * 64 + quad * 16));
                    c = __builtin_amdgcn_mfma_f32_16x16x32_bf16(kf, qf[ks], c, 0, 0, 0);
                }
                if (diag && st == rg) {
#pragma unroll
                    for (int r = 0; r < 4; ++r)
                        if (quad * 4 + r > l16) c[r] = -1e30f;
                }
                sa[st] = c;
            }
        }

        // online softmax for q-row l16 (state replicated across the 4 quads)
        float mloc = -1e30f;
#pragma unroll
        for (int st = 0; st < 4; ++st)
#pragma unroll
            for (int r = 0; r < 4; ++r) mloc = fmaxf(mloc, sa[st][r]);
        mloc = fmaxf(mloc, __shfl_xor(mloc, 16));
        mloc = fmaxf(mloc, __shfl_xor(mloc, 32));
        const float m_new = fmaxf(m_run, mloc);
        const float alpha = __expf(m_run - m_new);
        float p[4][4];
        float lsum = 0.f;
#pragma unroll
        for (int st = 0; st < 4; ++st)
#pragma unroll
            for (int r = 0; r < 4; ++r) {
                p[st][r] = __expf(sa[st][r] - m_new);
                lsum += p[st][r];
            }
        lsum += __shfl_xor(lsum, 16);
        lsum += __shfl_xor(lsum, 32);
        l_run = l_run * alpha + lsum;
        m_run = m_new;
#pragma unroll
        for (int i = 0; i < 8; ++i) acc_o[i] *= alpha;

        // P (C-layout) -> per-wave LDS -> P^T B-frags (same-wave, no barrier)
#pragma unroll
        for (int st = 0; st < 4; ++st) {
            uint2 pk;
            pk.x = pkbf(p[st][0], p[st][1]);
            pk.y = pkbf(p[st][2], p[st][3]);
            *(uint2*)(Pw + VSWZ(l16, st * 32 + quad * 8)) = pk;
        }
        bf16x8 pf0 = *(const bf16x8*)(Pw + VSWZ(l16, quad * 16));
        bf16x8 pf1 = *(const bf16x8*)(Pw + VSWZ(l16, 64 + quad * 16));

        // O^T += V^T . P^T
#pragma unroll
        for (int dt = 0; dt < 8; ++dt) {
            bf16x8 vf0 = *(const bf16x8*)(Vg + VSWZ(dt * 16 + l16, quad * 16));
            acc_o[dt] = __builtin_amdgcn_mfma_f32_16x16x32_bf16(vf0, pf0, acc_o[dt], 0, 0, 0);
            bf16x8 vf1 = *(const bf16x8*)(Vg + VSWZ(dt * 16 + l16, 64 + quad * 16));
            acc_o[dt] = __builtin_amdgcn_mfma_f32_16x16x32_bf16(vf1, pf1, acc_o[dt], 0, 0, 0);
        }
    }

    // ---- in-block flash combine: group 1 publishes (m,l,O); group 0 merges ----
    __syncthreads();
    if (g == 1) {
        float* dst = Ex + (rg * 16 + l16) * 128;
#pragma unroll
        for (int dt = 0; dt < 8; ++dt)
            *(f32x4*)&dst[dt * 16 + quad * 4] = acc_o[dt];
        if (quad == 0) {
            Em[rg * 16 + l16] = m_run;
            El[rg * 16 + l16] = l_run;
        }
    }
    __syncthreads();
    if (g == 0) {
        const float* src = Ex + (rg * 16 + l16) * 128;
        const float m2 = Em[rg * 16 + l16];
        const float l2 = El[rg * 16 + l16];
        const float ms = fmaxf(m_run, m2);
        const float a1 = __expf(m_run - ms);
        const float a2 = __expf(m2 - ms);
        const float linv = 1.f / (l_run * a1 + l2 * a2);
#pragma unroll
        for (int dt = 0; dt < 8; ++dt) {
            f32x4 o2 = *(const f32x4*)&src[dt * 16 + quad * 4];
            f32x4 v = (acc_o[dt] * a1 + o2 * a2) * linv;
            *(f32x4*)&Os[(rg * 16 + l16) * 132 + dt * 16 + quad * 4] = v;
        }
    }
    __syncthreads();
    // coalesced fp32 stores, all 512 threads
    float* dst = out + gbase + (size_t)(qt * 64) * Hn;
#pragma unroll
    for (int i = 0; i < 4; ++i) {
        const int idx = (t + i * 512) * 4;
        const int row = idx >> 7, col = idx & 127;
        *(float4*)&dst[row * 128 + col] = *(const float4*)&Os[row * 132 + col];
    }
}

// ---------------------------------------------------------------------------
extern "C" void kernel_launch(void* const* d_in, const int* in_sizes, int n_in,
                              void* d_out, int out_size, void* d_ws, size_t ws_size,
                              hipStream_t stream) {
    const float* x  = (const float*)d_in[0];
    const float* Wq = (const float*)d_in[1];
    const float* Wk = (const float*)d_in[2];
    const float* Wv = (const float*)d_in[3];
    float* o = (float*)d_out;            // output fp32 (verified round 4)

    unsigned short* Qb = (unsigned short*)d_ws;                 // (B*T, H) bf16
    unsigned short* Kb = Qb + (size_t)Bn * Tn * Hn;
    unsigned short* Vb = Kb + (size_t)Bn * Tn * Hn;

    static bool attr_done = false;
    if (!attr_done) {
        hipFuncSetAttribute((const void*)flash_mfma,
                            hipFuncAttributeMaxDynamicSharedMemorySize, 81920);
        attr_done = true;
    }

    qkv_mfma<<<dim3(256, 3), 256, 0, stream>>>(x, Wq, Wk, Wv, Qb, Kb, Vb);
    flash_mfma<<<dim3(8, 64), 512, 81920, stream>>>(Qb, Kb, Vb, o);
}